// Round 6
// baseline (246.371 us; speedup 1.0000x reference)
//
#include <hip/hip_runtime.h>
#include <hip/hip_bf16.h>
#include <math.h>

typedef __attribute__((ext_vector_type(8))) short short8;
typedef __attribute__((ext_vector_type(4))) float f32x4;

#define PSTRIDE 4160          // partials row stride in floats (non-pow2)
#define CHUNK_B 16384         // bytes per 128-k fragment chunk (64 rows x 128 k bf16)
#define SLAB_A_F 8388608u     // 512 chunks per A feature
#define SLAB_B_F 4194304u     // 256 chunks per B feature
#define LROW 528              // LDS row stride bytes (512 + 16 pad)

// round-to-nearest-even fp32 -> bf16 bits
__device__ __forceinline__ unsigned int bf16_rn(float x) {
    unsigned int u = __float_as_uint(x);
    return (u + 0x7FFFu + ((u >> 16) & 1u)) >> 16;
}

// ---------------------------------------------------------------------------
// Kernel 1: per-row cross-entropy + logits pass-through copy.
// ---------------------------------------------------------------------------
__global__ __launch_bounds__(256) void ce_kernel(
    const float* __restrict__ logits, const int* __restrict__ target,
    float* __restrict__ out_copy, float* __restrict__ ce_rows)
{
    const int row = blockIdx.x;
    const float* x = logits + row * 1000;
    const int t = threadIdx.x;
    __shared__ float red[256];

    float m = -INFINITY;
    for (int i = t; i < 1000; i += 256) {
        float v = x[i];
        out_copy[row * 1000 + i] = v;
        m = fmaxf(m, v);
    }
    red[t] = m; __syncthreads();
    for (int s = 128; s > 0; s >>= 1) {
        if (t < s) red[t] = fmaxf(red[t], red[t + s]);
        __syncthreads();
    }
    m = red[0];
    __syncthreads();

    float ssum = 0.f;
    for (int i = t; i < 1000; i += 256) ssum += expf(x[i] - m);
    red[t] = ssum; __syncthreads();
    for (int s = 128; s > 0; s >>= 1) {
        if (t < s) red[t] += red[t + s];
        __syncthreads();
    }
    if (t == 0) {
        double lse = (double)m + log((double)red[0]);
        int tg = target[row];
        ce_rows[row] = (float)(-((double)x[tg] - lse));
    }
}

// ---------------------------------------------------------------------------
// Kernel 2: repack fp32 -> bf16 slab in MFMA FRAGMENT ORDER via LDS transpose.
// Fragment layout per 128-k chunk c (16 KB):
//   offset = c*16384 + w*4096 + tm*1024 + lane*16, lane=(quad<<4)|m,
//   holding X[row=tm*16+m][k = c*128 + w*32 + quad*8 .. +7] as 8 bf16.
// Block = (feature, 256-k span): stage-1 reads one 1-KB granule per
// instruction (row-contiguous), converts, LDS (row stride 528 B, 2-way max);
// stage-2 gathers fragments from LDS and stores 1-KB coalesced granules.
// ---------------------------------------------------------------------------
__global__ __launch_bounds__(256) void repack_kernel(
    const float* __restrict__ A, const float* __restrict__ B,
    char* __restrict__ slab, int nfA, int nfB)
{
    __shared__ __align__(16) char lds[64 * LROW];   // 33792 B

    const int uA = nfA * 256;
    const int u = blockIdx.x;
    const float* xbase; char* slabF; int D, span;
    if (u < uA) {
        int f = u >> 8; span = u & 255; D = 65536;
        xbase = A + (size_t)f * 64 * D;
        slabF = slab + (size_t)f * SLAB_A_F;
    } else {
        int v = u - uA;
        int f = v >> 7; span = v & 127; D = 32768;
        xbase = B + (size_t)f * 64 * D;
        slabF = slab + (size_t)nfA * SLAB_A_F + (size_t)f * SLAB_B_F;
    }
    const int k0 = span * 256;
    const int wave = threadIdx.x >> 6, lane = threadIdx.x & 63;

    // ---- stage 1: 16 row-loads (each = one 1-KB contiguous granule) ----
    float4 v[16];
#pragma unroll
    for (int i = 0; i < 16; ++i) {
        int row = wave * 16 + i;
        v[i] = *(const float4*)(xbase + (size_t)row * D + k0 + lane * 4);
    }
#pragma unroll
    for (int i = 0; i < 16; ++i) {
        int row = wave * 16 + i;
        uint2 h;
        h.x = bf16_rn(v[i].x) | (bf16_rn(v[i].y) << 16);
        h.y = bf16_rn(v[i].z) | (bf16_rn(v[i].w) << 16);
        *(uint2*)(lds + row * LROW + lane * 8) = h;
    }
    __syncthreads();

    // ---- stage 2: fragment gather from LDS + coalesced 1-KB stores ----
    const int m = lane & 15;
#pragma unroll
    for (int cc = 0; cc < 2; ++cc) {
        const int c = span * 2 + cc;
#pragma unroll
        for (int tm = 0; tm < 4; ++tm) {
            int row = tm * 16 + m;
            int kl = cc * 128 + wave * 32 + ((lane >> 4) << 3);
            short8 s = *(const short8*)(lds + row * LROW + kl * 2);
            *(short8*)(slabF + (size_t)c * CHUNK_B + wave * 4096
                       + tm * 1024 + lane * 16) = s;
        }
    }
}

// ---------------------------------------------------------------------------
// Kernel 3: Gram from fragment slab. Every load = one 1-KB contiguous granule
// (base + tm*1024 + lane*16). Register-direct, no barriers in the loop,
// 2-chunk software pipeline. Block = (f, 8 chunks for A / 4 for B).
// ---------------------------------------------------------------------------
__global__ __launch_bounds__(256) void gram_kernel(
    const char* __restrict__ slab, float* __restrict__ partials,
    int nfA, int nfB)
{
    __shared__ float kbuf[4096];
    const int blk = blockIdx.x;
    const int f = blk >> 6, local = blk & 63;

    const char* slabF; int c0, nchunk;
    if (f < nfA) {
        slabF = slab + (size_t)f * SLAB_A_F; c0 = local * 8; nchunk = 8;
    } else {
        slabF = slab + (size_t)nfA * SLAB_A_F + (size_t)(f - nfA) * SLAB_B_F;
        c0 = local * 4; nchunk = 4;
    }

    const int t = threadIdx.x;
    const int wave = t >> 6, lane = t & 63;
    const int m = lane & 15, quad = lane >> 4;
    const char* base = slabF + (size_t)c0 * CHUNK_B + wave * 4096 + lane * 16;

    f32x4 acc[4][4];
#pragma unroll
    for (int i = 0; i < 4; ++i)
#pragma unroll
        for (int j = 0; j < 4; ++j) acc[i][j] = (f32x4)0.f;

    short8 cur[4], nxt[4];
#pragma unroll
    for (int tm = 0; tm < 4; ++tm)
        cur[tm] = *(const short8*)(base + tm * 1024);

    for (int ci = 0; ci < nchunk; ++ci) {
        if (ci + 1 < nchunk) {
            const char* nb = base + (size_t)(ci + 1) * CHUNK_B;
#pragma unroll
            for (int tm = 0; tm < 4; ++tm)
                nxt[tm] = *(const short8*)(nb + tm * 1024);
        }
#pragma unroll
        for (int tm = 0; tm < 4; ++tm)
#pragma unroll
            for (int tn = 0; tn < 4; ++tn)
                acc[tm][tn] = __builtin_amdgcn_mfma_f32_16x16x32_bf16(
                    cur[tm], cur[tn], acc[tm][tn], 0, 0, 0);
#pragma unroll
        for (int tm = 0; tm < 4; ++tm) cur[tm] = nxt[tm];
    }

    // ---- cross-wave reduce in LDS (C layout validated R2-R5) ----
    __syncthreads();
    if (wave == 0) {
#pragma unroll
        for (int tm = 0; tm < 4; ++tm)
#pragma unroll
            for (int tn = 0; tn < 4; ++tn)
#pragma unroll
                for (int r = 0; r < 4; ++r)
                    kbuf[(tm * 16 + quad * 4 + r) * 64 + tn * 16 + m] = acc[tm][tn][r];
    }
    __syncthreads();
    if (wave != 0) {
#pragma unroll
        for (int tm = 0; tm < 4; ++tm)
#pragma unroll
            for (int tn = 0; tn < 4; ++tn)
#pragma unroll
                for (int r = 0; r < 4; ++r)
                    atomicAdd(&kbuf[(tm * 16 + quad * 4 + r) * 64 + tn * 16 + m],
                              acc[tm][tn][r]);
    }
    __syncthreads();

    float4* outp = (float4*)(partials + (size_t)blk * PSTRIDE);
    const float4* kb4 = (const float4*)kbuf;
    for (int e = t; e < 1024; e += 256) outp[e] = kb4[e];
}

// ---------------------------------------------------------------------------
// Kernel 4: sum 64 partials per feature -> K[f], zero diagonal.
// ---------------------------------------------------------------------------
__global__ __launch_bounds__(256) void reduce_kernel(
    const float* __restrict__ partials, float* __restrict__ K, int singleF)
{
    __shared__ double red[256];
    int f, eblk, base;
    if (singleF < 0) { f = blockIdx.x >> 6; eblk = blockIdx.x & 63; base = f * 64; }
    else             { f = singleF; eblk = blockIdx.x; base = 0; }
    const int e = (eblk << 6) + (threadIdx.x & 63);
    const int jg = threadIdx.x >> 6;

    double s0 = 0.0, s1 = 0.0;
    for (int j = jg; j < 64; j += 8) {
        s0 += (double)partials[(size_t)(base + j) * PSTRIDE + e];
        s1 += (double)partials[(size_t)(base + j + 4) * PSTRIDE + e];
    }
    red[threadIdx.x] = s0 + s1;
    __syncthreads();
    if (jg == 0) {
        double tot = red[threadIdx.x] + red[threadIdx.x + 64]
                   + red[threadIdx.x + 128] + red[threadIdx.x + 192];
        int rr = e >> 6, cc = e & 63;
        K[f * 4096 + e] = (rr == cc) ? 0.f : (float)tot;
    }
}

// ---------------------------------------------------------------------------
// Kernel 5: ONE block -> all 25 HSIC pairs (fp64) + CE + final loss.
// ---------------------------------------------------------------------------
__global__ __launch_bounds__(256) void hsic_final_kernel(
    const float* __restrict__ K, const float* __restrict__ ce_rows,
    float* __restrict__ out_loss)
{
    __shared__ double rsum[7][64];
    __shared__ double ssum[7];
    __shared__ double trKL[25];
    __shared__ double wred[4];
    const int t = threadIdx.x;

    for (int task = t; task < 448; task += 256) {
        int f = task >> 6, n = task & 63;
        const float* Kf = K + f * 4096 + n * 64;
        double s = 0.0;
        for (int mc = 0; mc < 64; ++mc) s += (double)Kf[mc];
        rsum[f][n] = s;
    }
    __syncthreads();
    if (t < 7) {
        double s = 0.0;
        for (int n = 0; n < 64; ++n) s += rsum[t][n];
        ssum[t] = s;
    }

    for (int p = 0; p < 25; ++p) {
        int i, j;
        if (p < 9) { i = p / 3; j = p % 3; }
        else       { int q = p - 9; i = 3 + q / 4; j = 3 + q % 4; }
        const float* Ki = K + i * 4096;
        const float* Kj = K + j * 4096;
        double local = 0.0;
        for (int e = t; e < 4096; e += 256)
            local += (double)Ki[e] * (double)Kj[e];
        for (int off = 32; off > 0; off >>= 1)
            local += __shfl_down(local, off);
        if ((t & 63) == 0) wred[t >> 6] = local;
        __syncthreads();
        if (t == 0) trKL[p] = wred[0] + wred[1] + wred[2] + wred[3];
        __syncthreads();
    }

    if (t == 0) {
        double ce = 0.0;
        for (int n = 0; n < 64; ++n) ce += (double)ce_rows[n];
        ce /= 64.0;

        const double N = 64.0;
        const double c1 = (N - 1.0) * (N - 2.0);
        const double c2 = N - 2.0;
        const double c3 = N * (N - 3.0);
        double cka_total = 0.0;

        double hA[3][3];
        for (int p = 0; p < 9; ++p) {
            int i = p / 3, j = p % 3;
            double rr = 0.0;
            for (int n = 0; n < 64; ++n) rr += rsum[i][n] * rsum[j][n];
            hA[i][j] = (trKL[p] + ssum[i] * ssum[j] / c1 - 2.0 * rr / c2) / c3;
        }
        for (int i = 0; i < 3; ++i)
            for (int j = 0; j < 3; ++j)
                cka_total += hA[i][j] / sqrt(hA[i][i] * hA[j][j]);

        double hB[4][4];
        for (int q = 0; q < 16; ++q) {
            int i = q / 4, j = q % 4;
            double rr = 0.0;
            for (int n = 0; n < 64; ++n) rr += rsum[3 + i][n] * rsum[3 + j][n];
            hB[i][j] = (trKL[9 + q] + ssum[3 + i] * ssum[3 + j] / c1 - 2.0 * rr / c2) / c3;
        }
        for (int i = 0; i < 4; ++i)
            for (int j = 0; j < 4; ++j)
                cka_total += hB[i][j] / sqrt(hB[i][i] * hB[j][j]);

        out_loss[0] = (float)(ce + 0.1 * cka_total);
    }
}

// ---------------------------------------------------------------------------
extern "C" void kernel_launch(void* const* d_in, const int* in_sizes, int n_in,
                              void* d_out, int out_size, void* d_ws, size_t ws_size,
                              hipStream_t stream)
{
    const float* output  = (const float*)d_in[0];
    const int*   target  = (const int*)d_in[1];
    const float* feats_a = (const float*)d_in[2];
    const float* feats_b = (const float*)d_in[3];
    float* out = (float*)d_out;

    char* ws = (char*)d_ws;
    float*  K       = (float*)ws;                 // 114688 B
    float*  ce_rows = (float*)(ws + 114688);      // 256 B
    char*   slab    = ws + 131072;

    const size_t slabAll = 3 * (size_t)SLAB_A_F + 4 * (size_t)SLAB_B_F; // 41.9 MB
    const size_t partMain = (size_t)448 * PSTRIDE * 4;                  // 7.45 MB
    const size_t mainNeed = 131072 + slabAll + partMain;

    hipLaunchKernelGGL(ce_kernel, dim3(64), dim3(256), 0, stream,
                       output, target, out + 1, ce_rows);

    if (ws_size >= mainNeed) {
        // ---------------- one-shot path ----------------
        float* partials = (float*)(slab + slabAll);
        hipLaunchKernelGGL(repack_kernel, dim3(1280), dim3(256), 0, stream,
                           feats_a, feats_b, slab, 3, 4);
        hipLaunchKernelGGL(gram_kernel, dim3(448), dim3(256), 0, stream,
                           (const char*)slab, partials, 3, 4);
        hipLaunchKernelGGL(reduce_kernel, dim3(448), dim3(256), 0, stream,
                           partials, K, -1);
    } else {
        // ---------------- per-feature fallback (~9.3 MB) ----------------
        float* partials = (float*)(slab + SLAB_A_F);
        for (int f = 0; f < 7; ++f) {
            if (f < 3) {
                const float* X = feats_a + (size_t)f * 64 * 65536;
                hipLaunchKernelGGL(repack_kernel, dim3(256), dim3(256), 0, stream,
                                   X, (const float*)nullptr, slab, 1, 0);
                hipLaunchKernelGGL(gram_kernel, dim3(64), dim3(256), 0, stream,
                                   (const char*)slab, partials, 1, 0);
            } else {
                const float* X = feats_b + (size_t)(f - 3) * 64 * 32768;
                hipLaunchKernelGGL(repack_kernel, dim3(128), dim3(256), 0, stream,
                                   (const float*)nullptr, X, slab, 0, 1);
                hipLaunchKernelGGL(gram_kernel, dim3(64), dim3(256), 0, stream,
                                   (const char*)slab, partials, 0, 1);
            }
            hipLaunchKernelGGL(reduce_kernel, dim3(64), dim3(256), 0, stream,
                               partials, K, f);
        }
    }

    hipLaunchKernelGGL(hsic_final_kernel, dim3(1), dim3(256), 0, stream,
                       K, ce_rows, out);
}

// Round 7
// 241.798 us; speedup vs baseline: 1.0189x; 1.0189x over previous
//
#include <hip/hip_runtime.h>
#include <hip/hip_bf16.h>
#include <math.h>

typedef __attribute__((ext_vector_type(8))) short short8;
typedef __attribute__((ext_vector_type(4))) float f32x4;

#define CHUNK_B 16384         // bytes per 128-k fragment chunk (64 rows x 128 k bf16)
#define SLAB_A_F 8388608u     // 512 chunks per A feature
#define SLAB_B_F 4194304u     // 256 chunks per B feature
#define LROW 528              // LDS row stride bytes (512 + 16 pad)

// round-to-nearest-even fp32 -> bf16 bits
__device__ __forceinline__ unsigned int bf16_rn(float x) {
    unsigned int u = __float_as_uint(x);
    return (u + 0x7FFFu + ((u >> 16) & 1u)) >> 16;
}

// ---------------------------------------------------------------------------
// Kernel 1: per-row CE + logits pass-through copy + zero-init of K (so the
// gram kernel can accumulate into K with atomics; ws is poisoned 0xAA).
// ---------------------------------------------------------------------------
__global__ __launch_bounds__(256) void ce_kernel(
    const float* __restrict__ logits, const int* __restrict__ target,
    float* __restrict__ out_copy, float* __restrict__ ce_rows,
    float* __restrict__ K)
{
    const int row = blockIdx.x;
    const float* x = logits + row * 1000;
    const int t = threadIdx.x;
    __shared__ float red[256];

    // zero my slice of K (64 blocks x 448 = 28672 floats)
    for (int i = t; i < 448; i += 256) K[row * 448 + i] = 0.f;

    float m = -INFINITY;
    for (int i = t; i < 1000; i += 256) {
        float v = x[i];
        out_copy[row * 1000 + i] = v;
        m = fmaxf(m, v);
    }
    red[t] = m; __syncthreads();
    for (int s = 128; s > 0; s >>= 1) {
        if (t < s) red[t] = fmaxf(red[t], red[t + s]);
        __syncthreads();
    }
    m = red[0];
    __syncthreads();

    float ssum = 0.f;
    for (int i = t; i < 1000; i += 256) ssum += expf(x[i] - m);
    red[t] = ssum; __syncthreads();
    for (int s = 128; s > 0; s >>= 1) {
        if (t < s) red[t] += red[t + s];
        __syncthreads();
    }
    if (t == 0) {
        double lse = (double)m + log((double)red[0]);
        int tg = target[row];
        ce_rows[row] = (float)(-((double)x[tg] - lse));
    }
}

// ---------------------------------------------------------------------------
// Kernel 2: repack fp32 -> bf16 slab in MFMA fragment order via LDS transpose
// (unchanged from R6: both global sides are 1-KB-contiguous per instruction).
// ---------------------------------------------------------------------------
__global__ __launch_bounds__(256) void repack_kernel(
    const float* __restrict__ A, const float* __restrict__ B,
    char* __restrict__ slab, int nfA, int nfB)
{
    __shared__ __align__(16) char lds[64 * LROW];   // 33792 B

    const int uA = nfA * 256;
    const int u = blockIdx.x;
    const float* xbase; char* slabF; int D, span;
    if (u < uA) {
        int f = u >> 8; span = u & 255; D = 65536;
        xbase = A + (size_t)f * 64 * D;
        slabF = slab + (size_t)f * SLAB_A_F;
    } else {
        int v = u - uA;
        int f = v >> 7; span = v & 127; D = 32768;
        xbase = B + (size_t)f * 64 * D;
        slabF = slab + (size_t)nfA * SLAB_A_F + (size_t)f * SLAB_B_F;
    }
    const int k0 = span * 256;
    const int wave = threadIdx.x >> 6, lane = threadIdx.x & 63;

    // stage 1: 16 clustered row-loads (each one 1-KB contiguous granule)
    float4 v[16];
#pragma unroll
    for (int i = 0; i < 16; ++i) {
        int row = wave * 16 + i;
        v[i] = *(const float4*)(xbase + (size_t)row * D + k0 + lane * 4);
    }
#pragma unroll
    for (int i = 0; i < 16; ++i) {
        int row = wave * 16 + i;
        uint2 h;
        h.x = bf16_rn(v[i].x) | (bf16_rn(v[i].y) << 16);
        h.y = bf16_rn(v[i].z) | (bf16_rn(v[i].w) << 16);
        *(uint2*)(lds + row * LROW + lane * 8) = h;
    }
    __syncthreads();

    // stage 2: fragment gather from LDS + coalesced 1-KB stores
    const int m = lane & 15;
#pragma unroll
    for (int cc = 0; cc < 2; ++cc) {
        const int c = span * 2 + cc;
#pragma unroll
        for (int tm = 0; tm < 4; ++tm) {
            int row = tm * 16 + m;
            int kl = cc * 128 + wave * 32 + ((lane >> 4) << 3);
            short8 s = *(const short8*)(lds + row * LROW + kl * 2);
            *(short8*)(slabF + (size_t)c * CHUNK_B + wave * 4096
                       + tm * 1024 + lane * 16) = s;
        }
    }
}

// ---------------------------------------------------------------------------
// Kernel 3: Gram from fragment slab (single-granule loads, barrier-free
// pipelined K-loop, R6-validated). Epilogue: LDS cross-wave reduce, then
// atomicAdd the 64x64 tile into K[fBase+f], skipping the diagonal.
// ---------------------------------------------------------------------------
__global__ __launch_bounds__(256) void gram_kernel(
    const char* __restrict__ slab, float* __restrict__ K,
    int nfA, int nfB, int fBase)
{
    __shared__ float kbuf[4096];
    const int blk = blockIdx.x;
    const int f = blk >> 6, local = blk & 63;

    const char* slabF; int c0, nchunk;
    if (f < nfA) {
        slabF = slab + (size_t)f * SLAB_A_F; c0 = local * 8; nchunk = 8;
    } else {
        slabF = slab + (size_t)nfA * SLAB_A_F + (size_t)(f - nfA) * SLAB_B_F;
        c0 = local * 4; nchunk = 4;
    }

    const int t = threadIdx.x;
    const int wave = t >> 6, lane = t & 63;
    const int m = lane & 15, quad = lane >> 4;
    const char* base = slabF + (size_t)c0 * CHUNK_B + wave * 4096 + lane * 16;

    f32x4 acc[4][4];
#pragma unroll
    for (int i = 0; i < 4; ++i)
#pragma unroll
        for (int j = 0; j < 4; ++j) acc[i][j] = (f32x4)0.f;

    short8 cur[4], nxt[4];
#pragma unroll
    for (int tm = 0; tm < 4; ++tm)
        cur[tm] = *(const short8*)(base + tm * 1024);

    for (int ci = 0; ci < nchunk; ++ci) {
        if (ci + 1 < nchunk) {
            const char* nb = base + (size_t)(ci + 1) * CHUNK_B;
#pragma unroll
            for (int tm = 0; tm < 4; ++tm)
                nxt[tm] = *(const short8*)(nb + tm * 1024);
        }
#pragma unroll
        for (int tm = 0; tm < 4; ++tm)
#pragma unroll
            for (int tn = 0; tn < 4; ++tn)
                acc[tm][tn] = __builtin_amdgcn_mfma_f32_16x16x32_bf16(
                    cur[tm], cur[tn], acc[tm][tn], 0, 0, 0);
#pragma unroll
        for (int tm = 0; tm < 4; ++tm) cur[tm] = nxt[tm];
    }

    // cross-wave reduce in LDS (C layout validated R2-R6)
    __syncthreads();
    if (wave == 0) {
#pragma unroll
        for (int tm = 0; tm < 4; ++tm)
#pragma unroll
            for (int tn = 0; tn < 4; ++tn)
#pragma unroll
                for (int r = 0; r < 4; ++r)
                    kbuf[(tm * 16 + quad * 4 + r) * 64 + tn * 16 + m] = acc[tm][tn][r];
    }
    __syncthreads();
    if (wave != 0) {
#pragma unroll
        for (int tm = 0; tm < 4; ++tm)
#pragma unroll
            for (int tn = 0; tn < 4; ++tn)
#pragma unroll
                for (int r = 0; r < 4; ++r)
                    atomicAdd(&kbuf[(tm * 16 + quad * 4 + r) * 64 + tn * 16 + m],
                              acc[tm][tn][r]);
    }
    __syncthreads();

    // atomic accumulate into global K, diagonal skipped (K diag stays 0)
    float* Kf = K + (size_t)(fBase + f) * 4096;
    for (int e = t; e < 4096; e += 256)
        if ((e >> 6) != (e & 63)) atomicAdd(&Kf[e], kbuf[e]);
}

// ---------------------------------------------------------------------------
// Kernel 4: one 1024-thread block -> rowsums, 25 HSIC pairs (waves own pairs
// independently; coalesced reads; shuffle-only reduction), CE, final loss.
// ---------------------------------------------------------------------------
__global__ __launch_bounds__(1024) void tail_kernel(
    const float* __restrict__ K, const float* __restrict__ ce_rows,
    float* __restrict__ out_loss)
{
    __shared__ double rsum[448];
    __shared__ double ssum[7];
    __shared__ double trKL[25];
    const int t = threadIdx.x;

    if (t < 448) {                       // t = f*64 + n
        const float* Kr = K + t * 64;    // row n of feature f (diag already 0)
        double s = 0.0;
#pragma unroll 8
        for (int mc = 0; mc < 64; ++mc) s += (double)Kr[mc];
        rsum[t] = s;
    }
    __syncthreads();
    if (t < 7) {
        double s = 0.0;
        for (int n = 0; n < 64; ++n) s += rsum[t * 64 + n];
        ssum[t] = s;
    }

    const int wave = t >> 6, lane = t & 63;
    for (int p = wave; p < 25; p += 16) {
        int i, j;
        if (p < 9) { i = p / 3; j = p % 3; }
        else       { int q = p - 9; i = 3 + q / 4; j = 3 + q % 4; }
        const float* Ki = K + i * 4096;
        const float* Kj = K + j * 4096;
        double local = 0.0;
#pragma unroll 8
        for (int it = 0; it < 64; ++it) {
            int e = it * 64 + lane;
            local += (double)Ki[e] * (double)Kj[e];
        }
        for (int off = 32; off > 0; off >>= 1)
            local += __shfl_down(local, off);
        if (lane == 0) trKL[p] = local;
    }
    __syncthreads();

    if (t == 0) {
        double ce = 0.0;
        for (int n = 0; n < 64; ++n) ce += (double)ce_rows[n];
        ce /= 64.0;

        const double N = 64.0;
        const double c1 = (N - 1.0) * (N - 2.0);
        const double c2 = N - 2.0;
        const double c3 = N * (N - 3.0);
        double cka_total = 0.0;

        double hA[3][3];
        for (int p = 0; p < 9; ++p) {
            int i = p / 3, j = p % 3;
            double rr = 0.0;
            for (int n = 0; n < 64; ++n) rr += rsum[i * 64 + n] * rsum[j * 64 + n];
            hA[i][j] = (trKL[p] + ssum[i] * ssum[j] / c1 - 2.0 * rr / c2) / c3;
        }
        for (int i = 0; i < 3; ++i)
            for (int j = 0; j < 3; ++j)
                cka_total += hA[i][j] / sqrt(hA[i][i] * hA[j][j]);

        double hB[4][4];
        for (int q = 0; q < 16; ++q) {
            int i = q / 4, j = q % 4;
            double rr = 0.0;
            for (int n = 0; n < 64; ++n)
                rr += rsum[(3 + i) * 64 + n] * rsum[(3 + j) * 64 + n];
            hB[i][j] = (trKL[9 + q] + ssum[3 + i] * ssum[3 + j] / c1 - 2.0 * rr / c2) / c3;
        }
        for (int i = 0; i < 4; ++i)
            for (int j = 0; j < 4; ++j)
                cka_total += hB[i][j] / sqrt(hB[i][i] * hB[j][j]);

        out_loss[0] = (float)(ce + 0.1 * cka_total);
    }
}

// ---------------------------------------------------------------------------
extern "C" void kernel_launch(void* const* d_in, const int* in_sizes, int n_in,
                              void* d_out, int out_size, void* d_ws, size_t ws_size,
                              hipStream_t stream)
{
    const float* output  = (const float*)d_in[0];
    const int*   target  = (const int*)d_in[1];
    const float* feats_a = (const float*)d_in[2];
    const float* feats_b = (const float*)d_in[3];
    float* out = (float*)d_out;

    char* ws = (char*)d_ws;
    float*  K       = (float*)ws;                 // 114688 B
    float*  ce_rows = (float*)(ws + 114688);      // 256 B
    char*   slab    = ws + 131072;

    const size_t slabAll = 3 * (size_t)SLAB_A_F + 4 * (size_t)SLAB_B_F; // 41.9 MB
    const size_t mainNeed = 131072 + slabAll;

    // ce + zero K (must precede gram's atomic accumulation)
    hipLaunchKernelGGL(ce_kernel, dim3(64), dim3(256), 0, stream,
                       output, target, out + 1, ce_rows, K);

    if (ws_size >= mainNeed) {
        // ---------------- one-shot path: 4 dispatches total ----------------
        hipLaunchKernelGGL(repack_kernel, dim3(1280), dim3(256), 0, stream,
                           feats_a, feats_b, slab, 3, 4);
        hipLaunchKernelGGL(gram_kernel, dim3(448), dim3(256), 0, stream,
                           (const char*)slab, K, 3, 4, 0);
    } else {
        // ---------------- per-feature fallback (~8.5 MB) ----------------
        for (int f = 0; f < 7; ++f) {
            if (f < 3) {
                const float* X = feats_a + (size_t)f * 64 * 65536;
                hipLaunchKernelGGL(repack_kernel, dim3(256), dim3(256), 0, stream,
                                   X, (const float*)nullptr, slab, 1, 0);
                hipLaunchKernelGGL(gram_kernel, dim3(64), dim3(256), 0, stream,
                                   (const char*)slab, K, 1, 0, f);
            } else {
                const float* X = feats_b + (size_t)(f - 3) * 64 * 32768;
                hipLaunchKernelGGL(repack_kernel, dim3(128), dim3(256), 0, stream,
                                   (const float*)nullptr, X, slab, 0, 1);
                hipLaunchKernelGGL(gram_kernel, dim3(64), dim3(256), 0, stream,
                                   (const char*)slab, K, 0, 1, f);
            }
        }
    }

    hipLaunchKernelGGL(tail_kernel, dim3(1), dim3(1024), 0, stream,
                       K, ce_rows, out);
}

// Round 8
// 187.288 us; speedup vs baseline: 1.3155x; 1.2910x over previous
//
#include <hip/hip_runtime.h>
#include <hip/hip_bf16.h>
#include <math.h>

typedef __attribute__((ext_vector_type(8))) short short8;
typedef __attribute__((ext_vector_type(4))) float f32x4;

#define CHUNK_B 16384         // bytes per 128-k fragment chunk (64 rows x 128 k bf16)
#define SLAB_A_F 8388608u     // 512 chunks per A feature
#define SLAB_B_F 4194304u     // 256 chunks per B feature
#define LROW 528              // LDS row stride bytes (512 + 16 pad)

// round-to-nearest-even fp32 -> bf16 bits
__device__ __forceinline__ unsigned int bf16_rn(float x) {
    unsigned int u = __float_as_uint(x);
    return (u + 0x7FFFu + ((u >> 16) & 1u)) >> 16;
}

// ---------------------------------------------------------------------------
// Kernel 1: per-row CE + logits pass-through copy + zero-init of K (so the
// gram kernel can accumulate into K with atomics; ws is poisoned 0xAA).
// ---------------------------------------------------------------------------
__global__ __launch_bounds__(256) void ce_kernel(
    const float* __restrict__ logits, const int* __restrict__ target,
    float* __restrict__ out_copy, float* __restrict__ ce_rows,
    float* __restrict__ K)
{
    const int row = blockIdx.x;
    const float* x = logits + row * 1000;
    const int t = threadIdx.x;
    __shared__ float red[256];

    // zero my slice of K (64 blocks x 448 = 28672 floats)
    for (int i = t; i < 448; i += 256) K[row * 448 + i] = 0.f;

    float m = -INFINITY;
    for (int i = t; i < 1000; i += 256) {
        float v = x[i];
        out_copy[row * 1000 + i] = v;
        m = fmaxf(m, v);
    }
    red[t] = m; __syncthreads();
    for (int s = 128; s > 0; s >>= 1) {
        if (t < s) red[t] = fmaxf(red[t], red[t + s]);
        __syncthreads();
    }
    m = red[0];
    __syncthreads();

    float ssum = 0.f;
    for (int i = t; i < 1000; i += 256) ssum += expf(x[i] - m);
    red[t] = ssum; __syncthreads();
    for (int s = 128; s > 0; s >>= 1) {
        if (t < s) red[t] += red[t + s];
        __syncthreads();
    }
    if (t == 0) {
        double lse = (double)m + log((double)red[0]);
        int tg = target[row];
        ce_rows[row] = (float)(-((double)x[tg] - lse));
    }
}

// ---------------------------------------------------------------------------
// Kernel 2: repack fp32 -> bf16 slab in MFMA fragment order via LDS transpose
// (R6-validated: both global sides are 1-KB-contiguous per instruction).
// ---------------------------------------------------------------------------
__global__ __launch_bounds__(256) void repack_kernel(
    const float* __restrict__ A, const float* __restrict__ B,
    char* __restrict__ slab, int nfA, int nfB)
{
    __shared__ __align__(16) char lds[64 * LROW];   // 33792 B

    const int uA = nfA * 256;
    const int u = blockIdx.x;
    const float* xbase; char* slabF; int D, span;
    if (u < uA) {
        int f = u >> 8; span = u & 255; D = 65536;
        xbase = A + (size_t)f * 64 * D;
        slabF = slab + (size_t)f * SLAB_A_F;
    } else {
        int v = u - uA;
        int f = v >> 7; span = v & 127; D = 32768;
        xbase = B + (size_t)f * 64 * D;
        slabF = slab + (size_t)nfA * SLAB_A_F + (size_t)f * SLAB_B_F;
    }
    const int k0 = span * 256;
    const int wave = threadIdx.x >> 6, lane = threadIdx.x & 63;

    // stage 1: 16 clustered row-loads (each one 1-KB contiguous granule)
    float4 v[16];
#pragma unroll
    for (int i = 0; i < 16; ++i) {
        int row = wave * 16 + i;
        v[i] = *(const float4*)(xbase + (size_t)row * D + k0 + lane * 4);
    }
#pragma unroll
    for (int i = 0; i < 16; ++i) {
        int row = wave * 16 + i;
        uint2 h;
        h.x = bf16_rn(v[i].x) | (bf16_rn(v[i].y) << 16);
        h.y = bf16_rn(v[i].z) | (bf16_rn(v[i].w) << 16);
        *(uint2*)(lds + row * LROW + lane * 8) = h;
    }
    __syncthreads();

    // stage 2: fragment gather from LDS + coalesced 1-KB stores
    const int m = lane & 15;
#pragma unroll
    for (int cc = 0; cc < 2; ++cc) {
        const int c = span * 2 + cc;
#pragma unroll
        for (int tm = 0; tm < 4; ++tm) {
            int row = tm * 16 + m;
            int kl = cc * 128 + wave * 32 + ((lane >> 4) << 3);
            short8 s = *(const short8*)(lds + row * LROW + kl * 2);
            *(short8*)(slabF + (size_t)c * CHUNK_B + wave * 4096
                       + tm * 1024 + lane * 16) = s;
        }
    }
}

// ---------------------------------------------------------------------------
// Kernel 3: Gram from fragment slab (single-granule loads, barrier-free
// pipelined K-loop). Epilogue: LDS cross-wave reduce, then atomicAdd the
// 64x64 tile into K[fBase+f], skipping the diagonal.
// ---------------------------------------------------------------------------
__global__ __launch_bounds__(256) void gram_kernel(
    const char* __restrict__ slab, float* __restrict__ K,
    int nfA, int nfB, int fBase)
{
    __shared__ float kbuf[4096];
    const int blk = blockIdx.x;
    const int f = blk >> 6, local = blk & 63;

    const char* slabF; int c0, nchunk;
    if (f < nfA) {
        slabF = slab + (size_t)f * SLAB_A_F; c0 = local * 8; nchunk = 8;
    } else {
        slabF = slab + (size_t)nfA * SLAB_A_F + (size_t)(f - nfA) * SLAB_B_F;
        c0 = local * 4; nchunk = 4;
    }

    const int t = threadIdx.x;
    const int wave = t >> 6, lane = t & 63;
    const int m = lane & 15, quad = lane >> 4;
    const char* base = slabF + (size_t)c0 * CHUNK_B + wave * 4096 + lane * 16;

    f32x4 acc[4][4];
#pragma unroll
    for (int i = 0; i < 4; ++i)
#pragma unroll
        for (int j = 0; j < 4; ++j) acc[i][j] = (f32x4)0.f;

    short8 cur[4], nxt[4];
#pragma unroll
    for (int tm = 0; tm < 4; ++tm)
        cur[tm] = *(const short8*)(base + tm * 1024);

    for (int ci = 0; ci < nchunk; ++ci) {
        if (ci + 1 < nchunk) {
            const char* nb = base + (size_t)(ci + 1) * CHUNK_B;
#pragma unroll
            for (int tm = 0; tm < 4; ++tm)
                nxt[tm] = *(const short8*)(nb + tm * 1024);
        }
#pragma unroll
        for (int tm = 0; tm < 4; ++tm)
#pragma unroll
            for (int tn = 0; tn < 4; ++tn)
                acc[tm][tn] = __builtin_amdgcn_mfma_f32_16x16x32_bf16(
                    cur[tm], cur[tn], acc[tm][tn], 0, 0, 0);
#pragma unroll
        for (int tm = 0; tm < 4; ++tm) cur[tm] = nxt[tm];
    }

    // cross-wave reduce in LDS (C layout validated R2-R7)
    __syncthreads();
    if (wave == 0) {
#pragma unroll
        for (int tm = 0; tm < 4; ++tm)
#pragma unroll
            for (int tn = 0; tn < 4; ++tn)
#pragma unroll
                for (int r = 0; r < 4; ++r)
                    kbuf[(tm * 16 + quad * 4 + r) * 64 + tn * 16 + m] = acc[tm][tn][r];
    }
    __syncthreads();
    if (wave != 0) {
#pragma unroll
        for (int tm = 0; tm < 4; ++tm)
#pragma unroll
            for (int tn = 0; tn < 4; ++tn)
#pragma unroll
                for (int r = 0; r < 4; ++r)
                    atomicAdd(&kbuf[(tm * 16 + quad * 4 + r) * 64 + tn * 16 + m],
                              acc[tm][tn][r]);
    }
    __syncthreads();

    // atomic accumulate into global K, diagonal skipped (K diag stays 0)
    float* Kf = K + (size_t)(fBase + f) * 4096;
    for (int e = t; e < 4096; e += 256)
        if ((e >> 6) != (e & 63)) atomicAdd(&Kf[e], kbuf[e]);
}

// ---------------------------------------------------------------------------
// Kernel 4: one block per (i,j) pair -> unbiased HSIC in fp64.
// All loads coalesced: tr via lane-consecutive strides; rowsums via one
// full row per wave-instruction + shuffle reduce (no 64-granule loads).
// ---------------------------------------------------------------------------
__global__ __launch_bounds__(256) void hsic_kernel(
    const float* __restrict__ K, double* __restrict__ hsic_out)
{
    const int p = blockIdx.x;
    int i, j;
    if (p < 9) { i = p / 3; j = p % 3; }
    else       { int q = p - 9; i = 3 + q / 4; j = 3 + q % 4; }
    const float* Ki = K + i * 4096;
    const float* Kj = K + j * 4096;

    const int t = threadIdx.x;
    const int wave = t >> 6, lane = t & 63;

    __shared__ double wred[4];
    __shared__ double ri[64], rj[64];

    // ---- tr(Ki Kj): coalesced strided loads + shuffle reduce ----
    double local = 0.0;
#pragma unroll 4
    for (int e = t; e < 4096; e += 256)
        local += (double)Ki[e] * (double)Kj[e];
    for (int off = 32; off > 0; off >>= 1)
        local += __shfl_down(local, off);
    if (lane == 0) wred[wave] = local;

    // ---- rowsums: each wave-instruction reads ONE full row (1 granule set) ----
    const float* M = (wave < 2) ? Ki : Kj;
    double* R = (wave < 2) ? ri : rj;
    const int r0 = (wave & 1) * 32;
    for (int rr = 0; rr < 32; ++rr) {
        int row = r0 + rr;
        double v = (double)M[row * 64 + lane];
        for (int off = 32; off > 0; off >>= 1)
            v += __shfl_down(v, off);
        if (lane == 0) R[row] = v;
    }
    __syncthreads();

    if (t == 0) {
        double tr = wred[0] + wred[1] + wred[2] + wred[3];
        double rr = 0.0, si = 0.0, sj = 0.0;
        for (int n = 0; n < 64; ++n) {
            rr += ri[n] * rj[n];
            si += ri[n];
            sj += rj[n];
        }
        const double N = 64.0;
        const double c1 = (N - 1.0) * (N - 2.0);
        const double c2 = N - 2.0;
        const double c3 = N * (N - 3.0);
        hsic_out[p] = (tr + si * sj / c1 - 2.0 * rr / c2) / c3;
    }
}

// ---------------------------------------------------------------------------
// Kernel 5: combine -> loss (tiny fp64).
// ---------------------------------------------------------------------------
__global__ __launch_bounds__(64) void final_kernel(
    const double* __restrict__ hsic, const float* __restrict__ ce_rows,
    float* __restrict__ out_loss)
{
    const int lane = threadIdx.x;
    // parallel CE sum across the wave
    double cv = (double)ce_rows[lane];
    for (int off = 32; off > 0; off >>= 1)
        cv += __shfl_down(cv, off);
    if (lane != 0) return;
    double ce = cv / 64.0;

    double cka_total = 0.0;
    for (int i = 0; i < 3; ++i)
        for (int j = 0; j < 3; ++j)
            cka_total += hsic[i * 3 + j] / sqrt(hsic[i * 3 + i] * hsic[j * 3 + j]);
    for (int i = 0; i < 4; ++i)
        for (int j = 0; j < 4; ++j)
            cka_total += hsic[9 + i * 4 + j] / sqrt(hsic[9 + i * 4 + i] * hsic[9 + j * 4 + j]);

    out_loss[0] = (float)(ce + 0.1 * cka_total);
}

// ---------------------------------------------------------------------------
extern "C" void kernel_launch(void* const* d_in, const int* in_sizes, int n_in,
                              void* d_out, int out_size, void* d_ws, size_t ws_size,
                              hipStream_t stream)
{
    const float* output  = (const float*)d_in[0];
    const int*   target  = (const int*)d_in[1];
    const float* feats_a = (const float*)d_in[2];
    const float* feats_b = (const float*)d_in[3];
    float* out = (float*)d_out;

    char* ws = (char*)d_ws;
    float*  K       = (float*)ws;                 // 114688 B
    float*  ce_rows = (float*)(ws + 114688);      // 256 B
    double* hsic    = (double*)(ws + 114944);     // 256 B
    char*   slab    = ws + 131072;

    const size_t slabAll = 3 * (size_t)SLAB_A_F + 4 * (size_t)SLAB_B_F; // 41.9 MB
    const size_t mainNeed = 131072 + slabAll;

    // ce + zero K (must precede gram's atomic accumulation)
    hipLaunchKernelGGL(ce_kernel, dim3(64), dim3(256), 0, stream,
                       output, target, out + 1, ce_rows, K);

    if (ws_size >= mainNeed) {
        // ---------------- one-shot path: 5 dispatches total ----------------
        hipLaunchKernelGGL(repack_kernel, dim3(1280), dim3(256), 0, stream,
                           feats_a, feats_b, slab, 3, 4);
        hipLaunchKernelGGL(gram_kernel, dim3(448), dim3(256), 0, stream,
                           (const char*)slab, K, 3, 4, 0);
    } else {
        // ---------------- per-feature fallback (~8.5 MB) ----------------
        for (int f = 0; f < 7; ++f) {
            if (f < 3) {
                const float* X = feats_a + (size_t)f * 64 * 65536;
                hipLaunchKernelGGL(repack_kernel, dim3(256), dim3(256), 0, stream,
                                   X, (const float*)nullptr, slab, 1, 0);
                hipLaunchKernelGGL(gram_kernel, dim3(64), dim3(256), 0, stream,
                                   (const char*)slab, K, 1, 0, f);
            } else {
                const float* X = feats_b + (size_t)(f - 3) * 64 * 32768;
                hipLaunchKernelGGL(repack_kernel, dim3(128), dim3(256), 0, stream,
                                   (const float*)nullptr, X, slab, 0, 1);
                hipLaunchKernelGGL(gram_kernel, dim3(64), dim3(256), 0, stream,
                                   (const char*)slab, K, 0, 1, f);
            }
        }
    }

    hipLaunchKernelGGL(hsic_kernel, dim3(25), dim3(256), 0, stream, K, hsic);
    hipLaunchKernelGGL(final_kernel, dim3(1), dim3(64), 0, stream,
                       hsic, ce_rows, out);
}